// Round 4
// baseline (37.766 us; speedup 1.0000x reference)
//
#include <hip/hip_runtime.h>
#include <hip/hip_bf16.h>

// CosSim2D (K=3, same-pad, C=32 -> F=32) on MI355X.
// im2col-on-the-fly bf16 MFMA GEMM (M=pixels, K=288, N=32).
// Round 4: attack memory-transaction count + K-loop L2 latency.
//  - Cooperative staging: 8 lanes/pixel, contiguous float4 each -> 1KB fully
//    coalesced per wave-inst (was: 64 scattered 16B chunks per inst).
//  - All 18 B-fragments preloaded to VGPRs BEFORE staging (L2 latency hides
//    under staging+barrier); K-loop is pure LDS+MFMA.

#define H_ 224
#define W_ 224
#define C_ 32
#define F_ 32

#define NSTEP 18   // K = 288 = 18 * 16
#define HROWS 10   // staged halo rows (8 + 2)
#define HCOLS 34   // staged halo cols (32 + 2)

typedef __bf16 bf16_t;
typedef bf16_t bf16x8 __attribute__((ext_vector_type(8)));
typedef float f32x16 __attribute__((ext_vector_type(16)));

#define WFRAG_BYTES (NSTEP * 64 * 8 * 2)  // 18432 B

// ---------------- prep: w-norm + exponents + B-fragment swizzle -------------
__global__ __launch_bounds__(256) void cos2d_prep(
    const float* __restrict__ w, const float* __restrict__ p,
    const float* __restrict__ q, bf16_t* __restrict__ wfrag,
    float* __restrict__ winv, float* __restrict__ ef) {
  __shared__ float part[8][32];
  const int tid = threadIdx.x;
  const int f = tid & 31, kg = tid >> 5;  // 8 k-groups x 32 filters
  float s = 0.f;
#pragma unroll
  for (int i = 0; i < 36; ++i) {
    const float v = w[(kg + 8 * i) * F_ + f];
    s += v * v;
  }
  part[kg][f] = s;
  __syncthreads();
  if (tid < 32) {
    float t = 0.f;
#pragma unroll
    for (int g = 0; g < 8; ++g) t += part[g][tid];
    const float qt = q[0] * q[0] * 0.1f;
    winv[tid] = 1.f / (sqrtf(fmaxf(t, 1e-12f)) + qt);
    ef[tid] = p[tid] * p[tid] * 0.01f;
  }
  // B-fragment layout for mfma_f32_32x32x16_bf16:
  //   lane l holds col f = l&31, k = s2*16 + (l>>5)*8 + e  (e = 0..7).
  for (int t = tid; t < NSTEP * 64; t += 256) {
    const int s2 = t >> 6, l = t & 63;
    const int ff = l & 31;
    union { bf16_t v[8]; uint4 u; } tv;
#pragma unroll
    for (int e = 0; e < 8; ++e) {
      const int kk = s2 * 16 + ((l >> 5) << 3) + e;
      tv.v[e] = (bf16_t)w[kk * F_ + ff];
    }
    *(uint4*)(wfrag + (size_t)t * 8) = tv.u;
  }
}

// ---------------- main ------------------------------------------------------
__global__ __launch_bounds__(256, 4) void cos2d_main(
    const float* __restrict__ img, const bf16_t* __restrict__ wfrag,
    const float* __restrict__ winv, const float* __restrict__ ef,
    const float* __restrict__ q, float* __restrict__ out) {
  // pixel stride 40 bf16 = 80 B = 5x16B (aligned); 20-bank stride -> b128
  // quarter-wave groups hit 8 distinct banks (0 conflicts measured r2).
  __shared__ bf16_t xt[HROWS][HCOLS][40];
  __shared__ float ssum[HROWS][HCOLS];

  const int tid = threadIdx.x;
  const int lane = tid & 63;
  const int wv = tid >> 6;
  const int lp = lane & 31;

  const int bid = blockIdx.x;
  const int tw = bid % 7;
  const int th = (bid / 7) % 28;
  const int b  = bid / 196;
  const int h0 = th * 8, w0 = tw * 32;

  const float qt = q[0] * q[0] * 0.1f;
  const float efv = ef[lp];     // per-filter exponent (filter = lp)
  const float wnv = winv[lp];   // per-filter 1/(||w||+qt)

  // ---- preload ALL B fragments to VGPRs (issued first; L2 latency hides
  // under the staging phase + barrier). 72 VGPRs.
  bf16x8 bfrag[NSTEP];
  const bf16x8* wf4 = (const bf16x8*)wfrag;
#pragma unroll
  for (int s2 = 0; s2 < NSTEP; ++s2) bfrag[s2] = wf4[s2 * 64 + lane];

  // ---- cooperative coalesced staging: 8 lanes per pixel, lane sub reads
  // float4 #sub -> each wave-inst reads 1KB contiguous.
  for (int idx = tid; idx < HROWS * HCOLS * 8; idx += 256) {
    const int p = idx >> 3, sub = idx & 7;
    const int rr = p / HCOLS, cc = p - rr * HCOLS;
    const int hh = h0 - 1 + rr, wc = w0 - 1 + cc;
    float4 v = make_float4(0.f, 0.f, 0.f, 0.f);
    if ((unsigned)hh < H_ && (unsigned)wc < W_)
      v = *(const float4*)(img + ((size_t)(b * H_ + hh) * W_ + wc) * C_ + sub * 4);
    float s = v.x * v.x + v.y * v.y + v.z * v.z + v.w * v.w;
    s += __shfl_xor(s, 1);
    s += __shfl_xor(s, 2);
    s += __shfl_xor(s, 4);   // all 8 lanes of the group now hold the pixel sum
    union { bf16_t h[4]; uint2 u; } pk;
    pk.h[0] = (bf16_t)v.x; pk.h[1] = (bf16_t)v.y;
    pk.h[2] = (bf16_t)v.z; pk.h[3] = (bf16_t)v.w;
    *(uint2*)&xt[rr][cc][sub * 4] = pk.u;
    if (sub == 0) ssum[rr][cc] = s;
  }
  __syncthreads();

  const int mr0 = wv * 2;  // this wave's 2 output rows (tile-relative)

  // x_norm: 3x3 window sum of per-pixel channel sum-of-squares (fp32 exact)
  float xinv[2];
#pragma unroll
  for (int t = 0; t < 2; ++t) {
    const int mr = mr0 + t;
    const float xn2 = ssum[mr + 0][lp] + ssum[mr + 0][lp + 1] + ssum[mr + 0][lp + 2]
                    + ssum[mr + 1][lp] + ssum[mr + 1][lp + 1] + ssum[mr + 1][lp + 2]
                    + ssum[mr + 2][lp] + ssum[mr + 2][lp + 1] + ssum[mr + 2][lp + 2];
    xinv[t] = 1.f / (sqrtf(fmaxf(xn2, 1e-12f)) + qt);
  }

  f32x16 acc0, acc1;
#pragma unroll
  for (int i = 0; i < 16; ++i) { acc0[i] = 0.f; acc1[i] = 0.f; }

  // K loop: pure LDS + MFMA. A lane l -> pixel col = l&31, k = (l>>5)*8+e.
#pragma unroll
  for (int s2 = 0; s2 < NSTEP; ++s2) {
    const int pos = s2 >> 1;
    const int dy = pos / 3, dx = pos - dy * 3;
    const int chof = (s2 & 1) * 16 + ((lane >> 5) << 3);
    const bf16x8 a0 = *(const bf16x8*)&xt[mr0 + 0 + dy][lp + dx][chof];
    const bf16x8 a1 = *(const bf16x8*)&xt[mr0 + 1 + dy][lp + dx][chof];
    acc0 = __builtin_amdgcn_mfma_f32_32x32x16_bf16(a0, bfrag[s2], acc0, 0, 0, 0);
    acc1 = __builtin_amdgcn_mfma_f32_32x32x16_bf16(a1, bfrag[s2], acc1, 0, 0, 0);
  }

  // epilogue: C/D layout col = lane&31 (filter), row = (j&3)+8*(j>>2)+4*(lane>>5)
#pragma unroll
  for (int t = 0; t < 2; ++t) {
    const f32x16& acc = t ? acc1 : acc0;
    const int obase = (b * H_ + h0 + mr0 + t) * W_ + w0;
#pragma unroll
    for (int jj = 0; jj < 16; ++jj) {
      const int row = (jj & 3) + 8 * (jj >> 2) + 4 * (lane >> 5);
      const float xi = __shfl(xinv[t], row);  // xinv of pixel-col `row`
      const float sim = acc[jj] * xi * wnv;
      const float ps = fabsf(sim) + 1e-12f;
      float r = exp2f(efv * __log2f(ps));
      r = copysignf(r, sim);
      out[(size_t)(obase + row) * F_ + lp] = r;
    }
  }
}

// ---------------- launch ----------------------------------------------------
extern "C" void kernel_launch(void* const* d_in, const int* in_sizes, int n_in,
                              void* d_out, int out_size, void* d_ws, size_t ws_size,
                              hipStream_t stream) {
  const float* img = (const float*)d_in[0];
  const float* w   = (const float*)d_in[1];
  const float* p   = (const float*)d_in[2];
  const float* q   = (const float*)d_in[3];

  bf16_t* wfrag = (bf16_t*)d_ws;
  float*  winv  = (float*)((char*)d_ws + WFRAG_BYTES);
  float*  ef    = winv + 64;

  cos2d_prep<<<1, 256, 0, stream>>>(w, p, q, wfrag, winv, ef);
  // 8 images * 28 row-tiles * 7 col-tiles = 1568 blocks, 256 threads (4 waves)
  cos2d_main<<<1568, 256, 0, stream>>>(img, wfrag, winv, ef, q, (float*)d_out);
}